// Round 8
// baseline (218.607 us; speedup 1.0000x reference)
//
#include <hip/hip_runtime.h>

// Grouped_Soft_GSL_Block_PE fused kernel for MI355X (gfx950).
// B=8, IC2=128, N=2048, K=32, C=64, G=8, CPG=8, hidden=16.
// R8: 1024 blocks x 16 n (4 iters of 4 n), 256 thr / 4 waves; wave wv owns
// n = nblk + 4*it + wv. Zero barriers in loop.
// vs R7: xbuf deleted (B-fragments loaded DIRECTLY from global as scalars,
// 64B-coalesced per 16-lane group, cvt in regs); LDS cut to 54.1 KB and regs
// to ~165 targeting 3 blocks/CU x 3 waves/SIMD (__launch_bounds__(256,3));
// peW2/peBt fold precomputed by a prep kernel into d_ws; gab aliases h1b.

typedef __attribute__((ext_vector_type(8))) short bf16x8;
typedef __attribute__((ext_vector_type(4))) float f32x4;

#define EPS_BN 1e-5f

__device__ __forceinline__ unsigned pk2(float a, float b){
  unsigned ua = __float_as_uint(a) + 0x8000u;
  unsigned ub = __float_as_uint(b) + 0x8000u;
  return __builtin_amdgcn_perm(ub, ua, 0x07060302);
}
__device__ __forceinline__ short f2bf(float a){
  unsigned u = __float_as_uint(a);
  u += 0x7FFFu + ((u >> 16) & 1u);
  return (short)(u >> 16);
}
__device__ __forceinline__ float lrelu(float v){ return fmaxf(v, 0.2f*v); }

// paired-uint2 LDS store/load (8B-aligned; strides here are not 16B-aligned)
__device__ __forceinline__ void st8(short* dst, float4 a, float4 b){
  *(uint2*)(dst)     = make_uint2(pk2(a.x,a.y), pk2(a.z,a.w));
  *(uint2*)(dst + 4) = make_uint2(pk2(b.x,b.y), pk2(b.z,b.w));
}
__device__ __forceinline__ bf16x8 ld8(const short* p){
  union { bf16x8 v; uint2 q[2]; } w;
  w.q[0] = *(const uint2*)(p);
  w.q[1] = *(const uint2*)(p + 4);
  return w.v;
}

// DPP row_ror reductions over the 16-lane row (l15 = k dimension)
template<int N>
__device__ __forceinline__ float ror16(float x){
  return __int_as_float(__builtin_amdgcn_mov_dpp(__float_as_int(x), 0x120+N, 0xF, 0xF, false));
}
__device__ __forceinline__ float rsum16(float v){
  v += ror16<1>(v); v += ror16<2>(v); v += ror16<4>(v); v += ror16<8>(v); return v;
}
__device__ __forceinline__ float rmax16(float v){
  v = fmaxf(v, ror16<1>(v)); v = fmaxf(v, ror16<2>(v));
  v = fmaxf(v, ror16<4>(v)); v = fmaxf(v, ror16<8>(v)); return v;
}

#define MFMA16(a,b,c) __builtin_amdgcn_mfma_f32_16x16x32_bf16((a),(b),(c),0,0,0)

// direct global B-fragment load: 32 scalar f32 (chan = 32ks+8g4+j at one col)
__device__ __forceinline__ void loadfrag(float (&t)[32], const float* xc, long sg){
  #pragma unroll
  for (int ks = 0; ks < 4; ++ks)
    #pragma unroll
    for (int j = 0; j < 8; ++j)
      t[ks*8+j] = xc[(((long)(32*ks + j)) << 16) + sg];
}
__device__ __forceinline__ void cvtfrag(bf16x8 (&xb)[4], const float (&t)[32]){
  #pragma unroll
  for (int ks = 0; ks < 4; ++ks){
    union { bf16x8 v; unsigned u[4]; } w;
    w.u[0] = pk2(t[8*ks+0], t[8*ks+1]);
    w.u[1] = pk2(t[8*ks+2], t[8*ks+3]);
    w.u[2] = pk2(t[8*ks+4], t[8*ks+5]);
    w.u[3] = pk2(t[8*ks+6], t[8*ks+7]);
    xb[ks] = w.v;
  }
}

// prep: peW2 = pe_w @ pos_w2 (8x64) -> ws[0..511]; peBt -> ws[512..527]
__global__ void gsl_prep(const float* __restrict__ pos_w2, const float* __restrict__ pe_w,
                         const float* __restrict__ pe_b,   const float* __restrict__ pos_b2,
                         float* __restrict__ ws){
  int t = threadIdx.x;            // 0..511
  int r = t >> 6, j = t & 63;
  float s = 0.f;
  for (int c = 0; c < 64; ++c) s += pe_w[r*64 + c] * pos_w2[c*64 + j];
  ws[t] = s;
  if (t < 16){
    float v = 0.f;
    if (t < 8){
      v = pe_b[t];
      for (int c = 0; c < 64; ++c) v += pe_w[t*64 + c] * pos_b2[c];
    }
    ws[512 + t] = v;
  }
}

__global__ __launch_bounds__(256, 3)
void gsl_fused(const float* __restrict__ x,       const float* __restrict__ rel_pos,
               const float* __restrict__ pos_w1,  const float* __restrict__ pos_g,
               const float* __restrict__ pos_bb,  const float* __restrict__ pos_m,
               const float* __restrict__ pos_v,   const float* __restrict__ pos_w2,
               const float* __restrict__ pos_b2,  const float* __restrict__ trans_w,
               const float* __restrict__ tr_g,    const float* __restrict__ tr_bb,
               const float* __restrict__ tr_m,    const float* __restrict__ tr_v,
               const float* __restrict__ gate_w1, const float* __restrict__ ga_g,
               const float* __restrict__ ga_bb,   const float* __restrict__ ga_m,
               const float* __restrict__ ga_v,    const float* __restrict__ gate_w2,
               const float* __restrict__ gate_b2, const float* __restrict__ attn_w1,
               const float* __restrict__ at_g,    const float* __restrict__ at_bb,
               const float* __restrict__ at_m,    const float* __restrict__ at_v,
               const float* __restrict__ attn_w2, const float* __restrict__ attn_b2,
               const float* __restrict__ ws,      float* __restrict__ out)
{
  // LDS map (54080 B, 3 blocks/CU):
  // [0,25344)      wmain [96 rows][132] bf16 (trans 0..63, gate 64..79, attn 80..95)
  // [25344,35136)  wpos2 [72 rows][68] bf16 (0..63 pos_w2; 64..71 peW2 from ws;
  //                junk A-frag reads rows 72..79 land in h1b region - harmless)
  // [35136,52544)  h1b: per-wave 4352 B at wv*4352: [32 cols][68] bf16;
  //                gab [32][40] aliases it after pos2 (wave-sequential)
  // [52544,54080)  tabs f32: trT[128] pairs, pb2T[64], p1T[128] pairs,
  //                gaT[32], atT[32]
  __shared__ __align__(16) char smem[54080];
  short* wmain = (short*)smem;
  short* wpos2 = (short*)(smem + 25344);
  float* trT  = (float*)(smem + 52544);
  float* pb2T = (float*)(smem + 53056);
  float* p1T  = (float*)(smem + 53312);
  float* gaT  = (float*)(smem + 53824);
  float* atT  = (float*)(smem + 53952);

  const int tid = threadIdx.x;
  const int wv  = tid >> 6;
  const int l   = tid & 63;
  const int l15 = l & 15, g4 = l >> 4;
  const int bid = blockIdx.x;
  const int b    = bid >> 7;           // 128 blocks per batch
  const int nblk = (bid & 127) << 4;   // 16 n per block

  const int col0 = 32*wv + l15, col1 = col0 + 16;
  const int lc0 = l15, lc1 = l15 + 16;
  const float* xcg = x + (((long)(b*128 + 8*g4)) << 16);  // lane chan base
  const float* rpb = rel_pos + (((long)(3*b)) << 16);
  float* outb = out + (((long)(b*64)) << 11) + nblk + wv;
  short* h1b = (short*)(smem + 35136 + wv*4352);   // [32][68]
  short* gab = h1b;                                 // alias, used after pos2

  // ---- issue x prefetch for tile 0 (both coltiles) + rel_pos ----
  float t0[32], t1[32];
  float rc[6] = {0.f,0.f,0.f,0.f,0.f,0.f};
  {
    const long sb0 = (long)nblk * 32;
    loadfrag(t0, xcg, sb0 + col0);
    loadfrag(t1, xcg, sb0 + col0 + 16);
    if (g4 == 0){
      long sg = sb0 + col0;
      rc[0] = rpb[sg];          rc[1] = rpb[sg + 65536];      rc[2] = rpb[sg + 131072];
      rc[3] = rpb[sg + 16];     rc[4] = rpb[sg + 65536 + 16]; rc[5] = rpb[sg + 131072 + 16];
    }
  }

  // ---- stage weights -> LDS bf16 ----
  if (tid < 192){
    int r = tid >> 1, c0 = (tid & 1) * 64;
    const float* src = (r < 64) ? (trans_w + r*128)
                     : (r < 80) ? (gate_w1 + (r-64)*128)
                                : (attn_w1 + (r-80)*128);
    src += c0;
    short* dst = wmain + r*132 + c0;
    #pragma unroll
    for (int j = 0; j < 8; ++j)
      st8(dst + 8*j, *(const float4*)(src + 8*j), *(const float4*)(src + 8*j + 4));
  } else {
    int r = tid - 192;
    const float* src = pos_w2 + r*64;
    short* dst = wpos2 + r*68;
    #pragma unroll
    for (int j = 0; j < 8; ++j)
      st8(dst + 8*j, *(const float4*)(src + 8*j), *(const float4*)(src + 8*j + 4));
  }
  // peW2 rows 64..71 from ws
  if (tid < 16){
    int r = tid >> 1, c0 = (tid & 1) * 32;
    const float* src = ws + r*64 + c0;
    short* dst = wpos2 + (64 + r)*68 + c0;
    #pragma unroll
    for (int j = 0; j < 4; ++j)
      st8(dst + 8*j, *(const float4*)(src + 8*j), *(const float4*)(src + 8*j + 4));
  }
  // BN fold tables
  if (tid < 64){
    float s = tr_g[tid] * rsqrtf(tr_v[tid] + EPS_BN);
    trT[2*tid] = s; trT[2*tid+1] = tr_bb[tid] - tr_m[tid]*s;
    pb2T[tid] = pos_b2[tid];
    float s2 = pos_g[tid] * rsqrtf(pos_v[tid] + EPS_BN);
    p1T[2*tid] = s2; p1T[2*tid+1] = pos_bb[tid] - pos_m[tid]*s2;
  } else if (tid < 80){
    int c = tid - 64;
    float s = ga_g[c] * rsqrtf(ga_v[c] + EPS_BN);
    gaT[2*c] = s; gaT[2*c+1] = ga_bb[c] - ga_m[c]*s;
  } else if (tid < 96){
    int c = tid - 80;
    float s = at_g[c] * rsqrtf(at_v[c] + EPS_BN);
    atT[2*c] = s; atT[2*c+1] = at_bb[c] - at_m[c]*s;
  }

  // ---- small weights / consts -> registers ----
  uint2 pw1p[4];
  #pragma unroll
  for (int m2 = 0; m2 < 4; ++m2){
    uint2 t = make_uint2(0u, 0u);
    if (g4 == 0){
      const float* rp = pos_w1 + (16*m2 + l15)*3;
      t.x = pk2(rp[0], rp[1]);
      t.y = pk2(rp[2], 0.f);
    }
    pw1p[m2] = t;
  }
  bf16x8 gaf;
  {
    bf16x8 t = {0,0,0,0,0,0,0,0};
    #pragma unroll
    for (int j = 0; j < 8; ++j){
      int k = 8*g4 + j;
      float v2 = 0.f;
      if (l15 < 8)       { if (k >= 16) v2 = attn_w2[l15*16 + (k-16)]; }
      else if (l15 == 8) { if (k < 16)  v2 = gate_w2[k]; }
      t[j] = f2bf(v2);
    }
    gaf = t;
  }
  const float gb2v = gate_b2[0];
  float lcr[4];
  #pragma unroll
  for (int r = 0; r < 4; ++r){
    int row = 4*g4 + r;
    lcr[r] = ws[512 + row] + ((row < 8) ? attn_b2[row] : 0.f);
  }

  // cvt tile-0 prefetch -> bf16 fragment carry
  bf16x8 xb0[4], xb1[4];
  cvtfrag(xb0, t0);
  cvtfrag(xb1, t1);

  __syncthreads();   // LDS weights + tables visible

  for (int it = 0; it < 4; ++it){
    const long sbase = (long)nblk*32 + 128*it;
    const long nsb = sbase + ((it < 3) ? 128 : 0);

    // (1) main GEMM: [96x128] @ xtile, B from registers, A from wmain (b64 pairs)
    f32x4 acc[6][2];
    #pragma unroll
    for (int m = 0; m < 6; ++m){
      f32x4 z = {0.f,0.f,0.f,0.f};
      acc[m][0] = z; acc[m][1] = z;
    }
    #pragma unroll
    for (int ks = 0; ks < 4; ++ks){
      #pragma unroll
      for (int m = 0; m < 6; ++m){
        bf16x8 af = ld8(wmain + (16*m + l15)*132 + 32*ks + 8*g4);
        acc[m][0] = MFMA16(af, xb0[ks], acc[m][0]);
        acc[m][1] = MFMA16(af, xb1[ks], acc[m][1]);
      }
    }

    // (2) issue next-tile coltile0 loads (in flight across pos path)
    loadfrag(t0, xcg, nsb + col0);

    // (3) pos layer 1 (K padded 3->32) -> h1b ; uses rc of CURRENT iter
    {
      bf16x8 rf0 = {0,0,0,0,0,0,0,0}, rf1 = {0,0,0,0,0,0,0,0};
      if (g4 == 0){
        union { bf16x8 v; unsigned u[4]; } q0, q1;
        q0.u[0] = pk2(rc[0], rc[1]); q0.u[1] = pk2(rc[2], 0.f); q0.u[2] = 0u; q0.u[3] = 0u;
        q1.u[0] = pk2(rc[3], rc[4]); q1.u[1] = pk2(rc[5], 0.f); q1.u[2] = 0u; q1.u[3] = 0u;
        rf0 = q0.v; rf1 = q1.v;
      }
      #pragma unroll
      for (int m2 = 0; m2 < 4; ++m2){
        union { bf16x8 v; unsigned u[4]; } aw;
        aw.u[0] = pw1p[m2].x; aw.u[1] = pw1p[m2].y; aw.u[2] = 0u; aw.u[3] = 0u;
        f32x4 z = {0.f,0.f,0.f,0.f};
        f32x4 d0 = MFMA16(aw.v, rf0, z);
        f32x4 d1 = MFMA16(aw.v, rf1, z);
        int cb2 = 16*m2 + 4*g4;
        float2 q0 = *(const float2*)(p1T + 2*(cb2+0));
        float2 q1 = *(const float2*)(p1T + 2*(cb2+1));
        float2 q2 = *(const float2*)(p1T + 2*(cb2+2));
        float2 q3 = *(const float2*)(p1T + 2*(cb2+3));
        float h0 = lrelu(q0.x*d0[0]+q0.y), h1v = lrelu(q1.x*d0[1]+q1.y);
        float h2 = lrelu(q2.x*d0[2]+q2.y), h3 = lrelu(q3.x*d0[3]+q3.y);
        *(uint2*)(h1b + lc0*68 + cb2) = make_uint2(pk2(h0,h1v), pk2(h2,h3));
        h0 = lrelu(q0.x*d1[0]+q0.y); h1v = lrelu(q1.x*d1[1]+q1.y);
        h2 = lrelu(q2.x*d1[2]+q2.y); h3 = lrelu(q3.x*d1[3]+q3.y);
        *(uint2*)(h1b + lc1*68 + cb2) = make_uint2(pk2(h0,h1v), pk2(h2,h3));
      }
    }
    // (4) prefetch rel_pos for NEXT iter (after use)
    if (g4 == 0){
      long sg = nsb + col0;
      rc[0] = rpb[sg];          rc[1] = rpb[sg + 65536];      rc[2] = rpb[sg + 131072];
      rc[3] = rpb[sg + 16];     rc[4] = rpb[sg + 65536 + 16]; rc[5] = rpb[sg + 131072 + 16];
    }

    // (5) trans epilogue FIRST: acc[0..3] = lrelu(BN(conv)) + pos_b2
    #pragma unroll
    for (int m = 0; m < 4; ++m){
      float4 tb01 = *(const float4*)(trT + 2*(16*m + 4*g4));
      float4 tb23 = *(const float4*)(trT + 2*(16*m + 4*g4) + 4);
      float4 pz   = *(const float4*)(pb2T + 16*m + 4*g4);
      #pragma unroll
      for (int ct = 0; ct < 2; ++ct){
        acc[m][ct][0] = lrelu(tb01.x*acc[m][ct][0] + tb01.y) + pz.x;
        acc[m][ct][1] = lrelu(tb01.z*acc[m][ct][1] + tb01.w) + pz.y;
        acc[m][ct][2] = lrelu(tb23.x*acc[m][ct][2] + tb23.y) + pz.z;
        acc[m][ct][3] = lrelu(tb23.z*acc[m][ct][3] + tb23.w) + pz.w;
      }
    }

    // (6) pos2 MFMAs accumulate INTO acc[0..3]; pe-fold rows -> pac4
    f32x4 pac4[2];
    {
      f32x4 z = {0.f,0.f,0.f,0.f};
      pac4[0] = z; pac4[1] = z;
    }
    #pragma unroll
    for (int ks = 0; ks < 2; ++ks){
      bf16x8 h0 = ld8(h1b + lc0*68 + 32*ks + 8*g4);
      bf16x8 h1v = ld8(h1b + lc1*68 + 32*ks + 8*g4);
      #pragma unroll
      for (int m2 = 0; m2 < 4; ++m2){
        bf16x8 af = ld8(wpos2 + (16*m2 + l15)*68 + 32*ks + 8*g4);
        acc[m2][0] = MFMA16(af, h0, acc[m2][0]);
        acc[m2][1] = MFMA16(af, h1v, acc[m2][1]);
      }
      bf16x8 af4 = ld8(wpos2 + (64 + l15)*68 + 32*ks + 8*g4);
      pac4[0] = MFMA16(af4, h0, pac4[0]);
      pac4[1] = MFMA16(af4, h1v, pac4[1]);
    }

    // (7) cvt coltile0 prefetch -> xb0 ; issue coltile1 loads
    cvtfrag(xb0, t0);
    loadfrag(t1, xcg, nsb + col0 + 16);

    // (8) hidden epilogues -> gab (gate_h ch 0..15, attn_h ch 16..31)
    {
      int hc = 4*g4;
      float2 g0p = *(const float2*)(gaT + 2*(hc+0));
      float2 g1p = *(const float2*)(gaT + 2*(hc+1));
      float2 g2p = *(const float2*)(gaT + 2*(hc+2));
      float2 g3p = *(const float2*)(gaT + 2*(hc+3));
      float2 a0p = *(const float2*)(atT + 2*(hc+0));
      float2 a1p = *(const float2*)(atT + 2*(hc+1));
      float2 a2p = *(const float2*)(atT + 2*(hc+2));
      float2 a3p = *(const float2*)(atT + 2*(hc+3));
      #pragma unroll
      for (int ct = 0; ct < 2; ++ct){
        int lc = (ct == 0) ? lc0 : lc1;
        float q0 = lrelu(g0p.x*acc[4][ct][0] + g0p.y), q1 = lrelu(g1p.x*acc[4][ct][1] + g1p.y);
        float q2 = lrelu(g2p.x*acc[4][ct][2] + g2p.y), q3 = lrelu(g3p.x*acc[4][ct][3] + g3p.y);
        *(uint2*)(gab + lc*40 + hc) = make_uint2(pk2(q0,q1), pk2(q2,q3));
        float a0 = lrelu(a0p.x*acc[5][ct][0] + a0p.y), a1 = lrelu(a1p.x*acc[5][ct][1] + a1p.y);
        float a2 = lrelu(a2p.x*acc[5][ct][2] + a2p.y), a3 = lrelu(a3p.x*acc[5][ct][3] + a3p.y);
        *(uint2*)(gab + lc*40 + 16 + hc) = make_uint2(pk2(a0,a1), pk2(a2,a3));
      }
    }

    // (9) gate/attn layer-2 MFMA (rows 0..7 attn, row 8 gate)
    f32x4 gac0 = {0.f,0.f,0.f,0.f}, gac1 = gac0;
    {
      bf16x8 g0 = *(const bf16x8*)(gab + lc0*40 + 8*g4);
      bf16x8 g1 = *(const bf16x8*)(gab + lc1*40 + 8*g4);
      gac0 = MFMA16(gaf, g0, gac0);
      gac1 = MFMA16(gaf, g1, gac1);
    }

    // (10) gate, logits, softmax over k (DPP reduce), direct stores
    float gv0 = __shfl(gac0[0], 32 + l15, 64);
    float gv1 = __shfl(gac1[0], 32 + l15, 64);
    float gm0 = 1.f/(1.f + __expf(-(gv0 + gb2v)));
    float gm1 = 1.f/(1.f + __expf(-(gv1 + gb2v)));
    float lg0 = __logf(gm0 + 1e-6f), lg1 = __logf(gm1 + 1e-6f);

    float wg0[4], wg1[4];
    #pragma unroll
    for (int r = 0; r < 4; ++r){
      float tt0 = gac0[r] + pac4[0][r] + lcr[r] + lg0;
      float tt1 = gac1[r] + pac4[1][r] + lcr[r] + lg1;
      float mx = rmax16(fmaxf(tt0, tt1));
      float e0 = __expf(tt0 - mx), e1 = __expf(tt1 - mx);
      float inv = 1.f / rsum16(e0 + e1);
      wg0[r] = e0 * inv; wg1[r] = e1 * inv;
    }
    const bool hi = (g4 >= 2);
    #pragma unroll
    for (int m = 0; m < 4; ++m){
      // group pair (2m, 2m+1): both live in lanes src = 16*(m>>1)+l15
      int src = 16*(m >> 1) + l15;
      float a0 = __shfl(wg0[(2*m) & 3], src, 64);
      float b0 = __shfl(wg0[(2*m+1) & 3], src, 64);
      float a1 = __shfl(wg1[(2*m) & 3], src, 64);
      float b1 = __shfl(wg1[(2*m+1) & 3], src, 64);
      float w0 = hi ? b0 : a0;
      float w1 = hi ? b1 : a1;
      #pragma unroll
      for (int r = 0; r < 4; ++r){
        float sA = rsum16(acc[m][0][r]*w0 + acc[m][1][r]*w1);
        float sM = rmax16(fmaxf(acc[m][0][r]*gm0, acc[m][1][r]*gm1));
        if (l15 == 0)
          outb[(((long)(16*m + 4*g4 + r)) << 11) + 4*it] = sA + sM;
      }
    }

    // (11) cvt coltile1 prefetch -> xb1
    cvtfrag(xb1, t1);
  }
}

extern "C" void kernel_launch(void* const* d_in, const int* in_sizes, int n_in,
                              void* d_out, int out_size, void* d_ws, size_t ws_size,
                              hipStream_t stream){
  (void)in_sizes; (void)n_in; (void)out_size; (void)ws_size;
  gsl_prep<<<dim3(1), dim3(512), 0, stream>>>(
    (const float*)d_in[7], (const float*)d_in[9], (const float*)d_in[10],
    (const float*)d_in[8], (float*)d_ws);
  gsl_fused<<<dim3(1024), dim3(256), 0, stream>>>(
    (const float*)d_in[0],  (const float*)d_in[1],  (const float*)d_in[2],
    (const float*)d_in[3],  (const float*)d_in[4],  (const float*)d_in[5],
    (const float*)d_in[6],  (const float*)d_in[7],  (const float*)d_in[8],
    (const float*)d_in[11], (const float*)d_in[12], (const float*)d_in[13],
    (const float*)d_in[14], (const float*)d_in[15], (const float*)d_in[16],
    (const float*)d_in[17], (const float*)d_in[18], (const float*)d_in[19],
    (const float*)d_in[20], (const float*)d_in[21], (const float*)d_in[22],
    (const float*)d_in[23], (const float*)d_in[24], (const float*)d_in[25],
    (const float*)d_in[26], (const float*)d_in[27], (const float*)d_in[28],
    (const float*)d_in[29], (const float*)d_ws, (float*)d_out);
}

// Round 9
// 111.045 us; speedup vs baseline: 1.9686x; 1.9686x over previous
//
#include <hip/hip_runtime.h>

// Grouped_Soft_GSL_Block_PE fused kernel for MI355X (gfx950).
// B=8, IC2=128, N=2048, K=32, C=64, G=8, CPG=8, hidden=16.
// R9: wave-pair k-split. 1024 blocks x 16 n, 256 thr / 4 waves; iteration =
// 2 n; wave wv owns n = nblk+2it+(wv>>1), k-half 16*(wv&1)..+15 (16 cols =
// one MFMA B-frag). Per-wave regs ~halved vs R7 (acc[6][1], 32-f32 prefetch)
// -> (256,3) without spill; LDS 54528 B -> 3 blocks/CU = 12 waves/CU.
// Cross-wave softmax/out combines via small LDS exchanges, 3 barriers/iter.

typedef __attribute__((ext_vector_type(8))) short bf16x8;
typedef __attribute__((ext_vector_type(4))) float f32x4;

#define EPS_BN 1e-5f

__device__ __forceinline__ unsigned pk2(float a, float b){
  unsigned ua = __float_as_uint(a) + 0x8000u;
  unsigned ub = __float_as_uint(b) + 0x8000u;
  return __builtin_amdgcn_perm(ub, ua, 0x07060302);
}
__device__ __forceinline__ short f2bf(float a){
  unsigned u = __float_as_uint(a);
  u += 0x7FFFu + ((u >> 16) & 1u);
  return (short)(u >> 16);
}
__device__ __forceinline__ float lrelu(float v){ return fmaxf(v, 0.2f*v); }

// paired-uint2 LDS store/load (rows are 8B-aligned, not 16B)
__device__ __forceinline__ void st8(short* dst, float4 a, float4 b){
  *(uint2*)(dst)     = make_uint2(pk2(a.x,a.y), pk2(a.z,a.w));
  *(uint2*)(dst + 4) = make_uint2(pk2(b.x,b.y), pk2(b.z,b.w));
}
__device__ __forceinline__ bf16x8 ld8(const short* p){
  union { bf16x8 v; uint2 q[2]; } w;
  w.q[0] = *(const uint2*)(p);
  w.q[1] = *(const uint2*)(p + 4);
  return w.v;
}

// DPP row_ror reductions over the 16-lane row (l15 = k dimension)
template<int N>
__device__ __forceinline__ float ror16(float x){
  return __int_as_float(__builtin_amdgcn_mov_dpp(__float_as_int(x), 0x120+N, 0xF, 0xF, false));
}
__device__ __forceinline__ float rsum16(float v){
  v += ror16<1>(v); v += ror16<2>(v); v += ror16<4>(v); v += ror16<8>(v); return v;
}
__device__ __forceinline__ float rmax16(float v){
  v = fmaxf(v, ror16<1>(v)); v = fmaxf(v, ror16<2>(v));
  v = fmaxf(v, ror16<4>(v)); v = fmaxf(v, ror16<8>(v)); return v;
}

#define MFMA16(a,b,c) __builtin_amdgcn_mfma_f32_16x16x32_bf16((a),(b),(c),0,0,0)

// prep: pack pos_w2 A-fragments (bf16, frag-linear) + peW2 fragments + peBt
// ws layout: [0,8192) pos2 frags [m2][ks][lane] uint4
//            [8192,10240) pe frags [ks][lane] uint4 (rows 8..15 zero)
//            [10240,10304) peBt[16] f32
__global__ void gsl_prep(const float* __restrict__ pos_w2, const float* __restrict__ pe_w,
                         const float* __restrict__ pe_b,   const float* __restrict__ pos_b2,
                         char* __restrict__ ws){
  int t = threadIdx.x;   // 512 threads
  {
    int m2 = t >> 7, ks = (t >> 6) & 1, lane = t & 63;
    int l15 = lane & 15, g4 = lane >> 4;
    const float* src = pos_w2 + (16*m2 + l15)*64 + 32*ks + 8*g4;
    uint4 u;
    u.x = pk2(src[0], src[1]); u.y = pk2(src[2], src[3]);
    u.z = pk2(src[4], src[5]); u.w = pk2(src[6], src[7]);
    *(uint4*)(ws + t*16) = u;
  }
  if (t < 128){
    int ks = t >> 6, lane = t & 63;
    int l15 = lane & 15, g4 = lane >> 4;
    uint4 u = make_uint4(0u,0u,0u,0u);
    if (l15 < 8){
      float w[8];
      #pragma unroll
      for (int j = 0; j < 8; ++j){
        int c = 32*ks + 8*g4 + j;
        float s = 0.f;
        for (int k = 0; k < 64; ++k) s += pe_w[l15*64 + k] * pos_w2[k*64 + c];
        w[j] = s;
      }
      u.x = pk2(w[0],w[1]); u.y = pk2(w[2],w[3]);
      u.z = pk2(w[4],w[5]); u.w = pk2(w[6],w[7]);
    }
    *(uint4*)(ws + 8192 + t*16) = u;
  }
  if (t < 16){
    float v = 0.f;
    if (t < 8){
      v = pe_b[t];
      for (int c = 0; c < 64; ++c) v += pe_w[t*64 + c] * pos_b2[c];
    }
    *(float*)(ws + 10240 + t*4) = v;
  }
}

__global__ __launch_bounds__(256, 3)
void gsl_fused(const float* __restrict__ x,       const float* __restrict__ rel_pos,
               const float* __restrict__ pos_w1,  const float* __restrict__ pos_g,
               const float* __restrict__ pos_bb,  const float* __restrict__ pos_m,
               const float* __restrict__ pos_v,   const float* __restrict__ pos_b2,
               const float* __restrict__ trans_w, const float* __restrict__ tr_g,
               const float* __restrict__ tr_bb,   const float* __restrict__ tr_m,
               const float* __restrict__ tr_v,    const float* __restrict__ gate_w1,
               const float* __restrict__ ga_g,    const float* __restrict__ ga_bb,
               const float* __restrict__ ga_m,    const float* __restrict__ ga_v,
               const float* __restrict__ gate_w2, const float* __restrict__ gate_b2,
               const float* __restrict__ attn_w1, const float* __restrict__ at_g,
               const float* __restrict__ at_bb,   const float* __restrict__ at_m,
               const float* __restrict__ at_v,    const float* __restrict__ attn_w2,
               const float* __restrict__ attn_b2, const char* __restrict__ ws,
               float* __restrict__ out)
{
  // LDS map (54528 B, 3 blocks/CU):
  // [0,25344)      wmain [96][132] bf16 (trans 0..63, gate 64..79, attn 80..95)
  // [25344,42240)  xbuf [64 cols][132] bf16; wave slice 4224B at wv*4224
  //                (cols 16wv..16wv+15); aliased post-GEMM per wave:
  //                h1b [16][68] @slice, gab [16][40] @slice+2176
  // [42240,42496)  exchA (softmax max partials, 4 waves x 16 f)
  // [42496,42752)  exchB (softmax sum partials)
  // [42752,44800)  exch3 (output partials, 4 waves x 64 float2)
  // [44800,46336)  tabs f32: trT[128] pb2T[64] p1T[128] gaT[32] atT[32]
  // [46336,54528)  posf: pos2 A-frags (copy of ws[0,8192))
  __shared__ __align__(16) char smem[54528];
  short* wmain = (short*)smem;
  short* xbuf  = (short*)(smem + 25344);
  float* exchA = (float*)(smem + 42240);
  float* exchB = (float*)(smem + 42496);
  float* exch3 = (float*)(smem + 42752);
  float* trT  = (float*)(smem + 44800);
  float* pb2T = (float*)(smem + 45312);
  float* p1T  = (float*)(smem + 45568);
  float* gaT  = (float*)(smem + 46080);
  float* atT  = (float*)(smem + 46208);
  char*  posf = smem + 46336;

  const int tid = threadIdx.x;
  const int wv  = tid >> 6;          // wave 0..3; pair p = wv>>1, k-half = wv&1
  const int l   = tid & 63;
  const int l15 = l & 15, g4 = l >> 4;
  const int bid = blockIdx.x;
  const int b    = bid >> 7;          // 128 blocks per batch
  const int nblk = (bid & 127) << 4;  // 16 n per block

  // ---- stage wmain -> LDS bf16 ; copy posf from ws ----
  if (tid < 192){
    int r = tid >> 1, c0 = (tid & 1) * 64;
    const float* src = (r < 64) ? (trans_w + r*128)
                     : (r < 80) ? (gate_w1 + (r-64)*128)
                                : (attn_w1 + (r-80)*128);
    src += c0;
    short* dst = wmain + r*132 + c0;
    #pragma unroll
    for (int j = 0; j < 8; ++j)
      st8(dst + 8*j, *(const float4*)(src + 8*j), *(const float4*)(src + 8*j + 4));
  }
  {
    const uint4* s4 = (const uint4*)ws;
    uint4* d4 = (uint4*)posf;
    d4[tid]       = s4[tid];
    d4[tid + 256] = s4[tid + 256];
  }
  // ---- BN fold tables ----
  if (tid < 64){
    float s = tr_g[tid] * rsqrtf(tr_v[tid] + EPS_BN);
    trT[2*tid] = s; trT[2*tid+1] = tr_bb[tid] - tr_m[tid]*s;
    pb2T[tid] = pos_b2[tid];
    float s2 = pos_g[tid] * rsqrtf(pos_v[tid] + EPS_BN);
    p1T[2*tid] = s2; p1T[2*tid+1] = pos_bb[tid] - pos_m[tid]*s2;
  } else if (tid < 80){
    int c = tid - 64;
    float s = ga_g[c] * rsqrtf(ga_v[c] + EPS_BN);
    gaT[2*c] = s; gaT[2*c+1] = ga_bb[c] - ga_m[c]*s;
  } else if (tid < 96){
    int c = tid - 80;
    float s = at_g[c] * rsqrtf(at_v[c] + EPS_BN);
    atT[2*c] = s; atT[2*c+1] = at_bb[c] - at_m[c]*s;
  }

  // ---- small weights / consts -> registers ----
  uint2 pw1p[4];
  #pragma unroll
  for (int m2 = 0; m2 < 4; ++m2){
    uint2 t = make_uint2(0u, 0u);
    if (g4 == 0){
      const float* rp = pos_w1 + (16*m2 + l15)*3;
      t.x = pk2(rp[0], rp[1]);
      t.y = pk2(rp[2], 0.f);
    }
    pw1p[m2] = t;
  }
  bf16x8 gaf;
  {
    bf16x8 t = {0,0,0,0,0,0,0,0};
    #pragma unroll
    for (int j = 0; j < 8; ++j){
      int k = 8*g4 + j;
      float v2 = 0.f;
      if (l15 < 8)       { if (k >= 16) v2 = attn_w2[l15*16 + (k-16)]; }
      else if (l15 == 8) { if (k < 16)  v2 = gate_w2[k]; }
      t[j] = f2bf(v2);
    }
    gaf = t;
  }
  bf16x8 pef[2];
  #pragma unroll
  for (int ks = 0; ks < 2; ++ks)
    pef[ks] = *(const bf16x8*)(ws + 8192 + (ks*64 + l)*16);
  const float gb2v = gate_b2[0];
  float lcr[4];
  #pragma unroll
  for (int r = 0; r < 4; ++r){
    int row = 4*g4 + r;
    lcr[r] = *(const float*)(ws + 10240 + row*4) + ((row < 8) ? attn_b2[row] : 0.f);
  }

  // ---- per-wave constants ----
  const int q = l & 3, d = l >> 2;            // staging: col-quad 4q, chans 8d..8d+7
  const long sg0 = (long)nblk*32 + 16*wv;     // wave's first spatial col (iter 0)
  const float* xpq = x + (((long)(b*128 + 8*d)) << 16) + sg0 + 4*q;
  const float* rpb = rel_pos + (((long)(3*b)) << 16);
  short* slice = xbuf + wv*2112;              // 16 rows x 132 shorts
  short* h1b = slice;                          // [16][68]
  short* gab = slice + 1088;                   // [16][40] @ +2176B
  float* e3own = exch3 + wv*128;               // 64 float2

  // ---- prologue: prefetch iteration 0 ----
  f32x4 fa[4], fb[4];
  float rc[3] = {0.f,0.f,0.f};
  #pragma unroll
  for (int j = 0; j < 4; ++j) fa[j] = *(const f32x4*)(xpq + (((long)j) << 16));
  #pragma unroll
  for (int j = 0; j < 4; ++j) fb[j] = *(const f32x4*)(xpq + (((long)(4+j)) << 16));
  if (g4 == 0){
    long sgr = sg0 + l15;
    rc[0] = rpb[sgr]; rc[1] = rpb[sgr + 65536]; rc[2] = rpb[sgr + 131072];
  }

  __syncthreads();   // LDS weights + tables + posf visible

  for (int it = 0; it < 8; ++it){
    const long ofs = 64*(long)it;
    const long nofs = ofs + ((it < 7) ? 64 : 0);

    // (1) cvt + write staged 16-col tile -> own xbuf slice
    #pragma unroll
    for (int i = 0; i < 4; ++i){
      short* dst = xbuf + (16*wv + 4*q + i)*132 + 8*d;
      *(uint2*)(dst)     = make_uint2(pk2(fa[0][i],fa[1][i]), pk2(fa[2][i],fa[3][i]));
      *(uint2*)(dst + 4) = make_uint2(pk2(fb[0][i],fb[1][i]), pk2(fb[2][i],fb[3][i]));
    }

    // (2) prefetch fa half for next iter
    #pragma unroll
    for (int j = 0; j < 4; ++j) fa[j] = *(const f32x4*)(xpq + nofs + (((long)j) << 16));

    // (3) main GEMM: [96x128] @ xtile(16 cols)
    f32x4 acc[6];
    #pragma unroll
    for (int m = 0; m < 6; ++m){ f32x4 z = {0.f,0.f,0.f,0.f}; acc[m] = z; }
    #pragma unroll
    for (int ks = 0; ks < 4; ++ks){
      bf16x8 xb = ld8(xbuf + (16*wv + l15)*132 + 32*ks + 8*g4);
      #pragma unroll
      for (int m = 0; m < 6; ++m){
        bf16x8 af = ld8(wmain + (16*m + l15)*132 + 32*ks + 8*g4);
        acc[m] = MFMA16(af, xb, acc[m]);
      }
    }

    // (4) prefetch fb half for next iter
    #pragma unroll
    for (int j = 0; j < 4; ++j) fb[j] = *(const f32x4*)(xpq + nofs + (((long)(4+j)) << 16));

    // (5) pos layer 1 (K padded 3->32) -> h1b
    {
      bf16x8 rf = {0,0,0,0,0,0,0,0};
      if (g4 == 0){
        union { bf16x8 v; unsigned u[4]; } t;
        t.u[0] = pk2(rc[0], rc[1]); t.u[1] = pk2(rc[2], 0.f); t.u[2] = 0u; t.u[3] = 0u;
        rf = t.v;
      }
      #pragma unroll
      for (int m2 = 0; m2 < 4; ++m2){
        union { bf16x8 v; unsigned u[4]; } aw;
        aw.u[0] = pw1p[m2].x; aw.u[1] = pw1p[m2].y; aw.u[2] = 0u; aw.u[3] = 0u;
        f32x4 z = {0.f,0.f,0.f,0.f};
        f32x4 d0 = MFMA16(aw.v, rf, z);
        int cb2 = 16*m2 + 4*g4;
        float2 t0 = *(const float2*)(p1T + 2*(cb2+0));
        float2 t1 = *(const float2*)(p1T + 2*(cb2+1));
        float2 t2 = *(const float2*)(p1T + 2*(cb2+2));
        float2 t3 = *(const float2*)(p1T + 2*(cb2+3));
        float h0 = lrelu(t0.x*d0[0]+t0.y), h1v = lrelu(t1.x*d0[1]+t1.y);
        float h2 = lrelu(t2.x*d0[2]+t2.y), h3 = lrelu(t3.x*d0[3]+t3.y);
        *(uint2*)(h1b + l15*68 + cb2) = make_uint2(pk2(h0,h1v), pk2(h2,h3));
      }
    }
    // (5b) prefetch rel_pos for next iter
    if (g4 == 0){
      long sgr = sg0 + nofs + l15;
      rc[0] = rpb[sgr]; rc[1] = rpb[sgr + 65536]; rc[2] = rpb[sgr + 131072];
    }

    // (6) trans epilogue: acc[0..3] = lrelu(BN(conv)) + pos_b2
    #pragma unroll
    for (int m = 0; m < 4; ++m){
      float4 tb01 = *(const float4*)(trT + 2*(16*m + 4*g4));
      float4 tb23 = *(const float4*)(trT + 2*(16*m + 4*g4) + 4);
      float4 pz   = *(const float4*)(pb2T + 16*m + 4*g4);
      acc[m][0] = lrelu(tb01.x*acc[m][0] + tb01.y) + pz.x;
      acc[m][1] = lrelu(tb01.z*acc[m][1] + tb01.w) + pz.y;
      acc[m][2] = lrelu(tb23.x*acc[m][2] + tb23.y) + pz.z;
      acc[m][3] = lrelu(tb23.z*acc[m][3] + tb23.w) + pz.w;
    }

    // (7) pos2 accumulates INTO acc[0..3] (A-frags from posf); pe -> pac4
    f32x4 pac4 = {0.f,0.f,0.f,0.f};
    #pragma unroll
    for (int ks = 0; ks < 2; ++ks){
      bf16x8 h = ld8(h1b + l15*68 + 32*ks + 8*g4);
      #pragma unroll
      for (int m2 = 0; m2 < 4; ++m2){
        bf16x8 af = *(const bf16x8*)(posf + ((m2*2 + ks)*64 + l)*16);
        acc[m2] = MFMA16(af, h, acc[m2]);
      }
      pac4 = MFMA16(pef[ks], h, pac4);
    }

    // (8) hidden epilogues -> gab (gate_h ch 0..15, attn_h ch 16..31)
    {
      int hc = 4*g4;
      float2 g0p = *(const float2*)(gaT + 2*(hc+0));
      float2 g1p = *(const float2*)(gaT + 2*(hc+1));
      float2 g2p = *(const float2*)(gaT + 2*(hc+2));
      float2 g3p = *(const float2*)(gaT + 2*(hc+3));
      float q0 = lrelu(g0p.x*acc[4][0] + g0p.y), q1 = lrelu(g1p.x*acc[4][1] + g1p.y);
      float q2 = lrelu(g2p.x*acc[4][2] + g2p.y), q3 = lrelu(g3p.x*acc[4][3] + g3p.y);
      *(uint2*)(gab + l15*40 + hc) = make_uint2(pk2(q0,q1), pk2(q2,q3));
      float2 a0p = *(const float2*)(atT + 2*(hc+0));
      float2 a1p = *(const float2*)(atT + 2*(hc+1));
      float2 a2p = *(const float2*)(atT + 2*(hc+2));
      float2 a3p = *(const float2*)(atT + 2*(hc+3));
      float a0 = lrelu(a0p.x*acc[5][0] + a0p.y), a1 = lrelu(a1p.x*acc[5][1] + a1p.y);
      float a2 = lrelu(a2p.x*acc[5][2] + a2p.y), a3 = lrelu(a3p.x*acc[5][3] + a3p.y);
      *(uint2*)(gab + l15*40 + 16 + hc) = make_uint2(pk2(a0,a1), pk2(a2,a3));
    }

    // (9) gate/attn layer-2 MFMA (rows 0..7 attn, row 8 gate)
    f32x4 gac = {0.f,0.f,0.f,0.f};
    {
      bf16x8 g0 = *(const bf16x8*)(gab + l15*40 + 8*g4);
      gac = MFMA16(gaf, g0, gac);
    }

    // (10) gate + logits + cross-wave softmax (exchA/exchB)
    float gv = __shfl(gac[0], 32 + l15, 64);
    float gm = 1.f/(1.f + __expf(-(gv + gb2v)));
    float lg = __logf(gm + 1e-6f);

    float tl[4];
    #pragma unroll
    for (int r = 0; r < 4; ++r){
      tl[r] = gac[r] + pac4[r] + lcr[r] + lg;
      float pm = rmax16(tl[r]);
      if (l15 == 0) exchA[wv*16 + 4*g4 + r] = pm;
    }
    __syncthreads();                       // bar1: maxes visible
    float e[4], ps[4];
    #pragma unroll
    for (int r = 0; r < 4; ++r){
      float pmx = fmaxf(rmax16(tl[r]), exchA[(wv^1)*16 + 4*g4 + r]);
      e[r] = __expf(tl[r] - pmx);
      ps[r] = rsum16(e[r]);
      if (l15 == 0) exchB[wv*16 + 4*g4 + r] = ps[r];
    }
    __syncthreads();                       // bar2: sums visible
    float wg[4];
    #pragma unroll
    for (int r = 0; r < 4; ++r){
      float stot = ps[r] + exchB[(wv^1)*16 + 4*g4 + r];
      wg[r] = e[r] / stot;
    }

    // (11) weighted partial sums -> own exch3
    const bool hi = (g4 >= 2);
    #pragma unroll
    for (int m = 0; m < 4; ++m){
      int gg0 = 2*m, gg1 = 2*m + 1;
      float a0 = __shfl(wg[gg0 & 3], 16*(gg0 >> 2) + l15, 64);
      float b0 = __shfl(wg[gg1 & 3], 16*(gg1 >> 2) + l15, 64);
      float w = hi ? b0 : a0;
      #pragma unroll
      for (int r = 0; r < 4; ++r){
        float sA = rsum16(acc[m][r] * w);
        float sM = rmax16(fmaxf(acc[m][r]*gm, acc[m][r]*gm));  // feat*gm max
        if (l15 == 0){
          int ch = 16*m + 4*g4 + r;
          e3own[2*ch]   = sA;
          e3own[2*ch+1] = sM;
        }
      }
    }
    __syncthreads();                       // bar3: partials visible

    // (12) even wave of each pair combines + stores (one ch per lane)
    if (!(wv & 1)){
      const float* p3 = exch3 + (wv + 1)*128;
      float vA = e3own[2*l]   + p3[2*l];
      float vM = fmaxf(e3own[2*l+1], p3[2*l+1]);
      int n = nblk + 2*it + (wv >> 1);
      out[(((long)(b*64 + l)) << 11) + n] = vA + vM;
    }
  }
}

extern "C" void kernel_launch(void* const* d_in, const int* in_sizes, int n_in,
                              void* d_out, int out_size, void* d_ws, size_t ws_size,
                              hipStream_t stream){
  (void)in_sizes; (void)n_in; (void)out_size; (void)ws_size;
  gsl_prep<<<dim3(1), dim3(512), 0, stream>>>(
    (const float*)d_in[7], (const float*)d_in[9], (const float*)d_in[10],
    (const float*)d_in[8], (char*)d_ws);
  gsl_fused<<<dim3(1024), dim3(256), 0, stream>>>(
    (const float*)d_in[0],  (const float*)d_in[1],  (const float*)d_in[2],
    (const float*)d_in[3],  (const float*)d_in[4],  (const float*)d_in[5],
    (const float*)d_in[6],  (const float*)d_in[8],  (const float*)d_in[11],
    (const float*)d_in[12], (const float*)d_in[13], (const float*)d_in[14],
    (const float*)d_in[15], (const float*)d_in[16], (const float*)d_in[17],
    (const float*)d_in[18], (const float*)d_in[19], (const float*)d_in[20],
    (const float*)d_in[21], (const float*)d_in[22], (const float*)d_in[23],
    (const float*)d_in[24], (const float*)d_in[25], (const float*)d_in[26],
    (const float*)d_in[27], (const float*)d_in[28], (const float*)d_in[29],
    (const char*)d_ws, (float*)d_out);
}

// Round 10
// 75.441 us; speedup vs baseline: 2.8977x; 1.4719x over previous
//
#include <hip/hip_runtime.h>

// Grouped_Soft_GSL_Block_PE fused kernel for MI355X (gfx950).
// B=8, IC2=128, N=2048, K=32, C=64, G=8, CPG=8, hidden=16.
// R10: R7 structure (512 blocks, 256 thr / 4 waves, block owns 32 n,
// 8 iterations of 4 n, wave wv owns n = nblk+4it+wv, zero barriers in loop)
// with bank-conflict-optimal LDS strides: 136->132 (xbuf,wmain), 72->68
// (wpos2,h1b), 40->36 (gab). Stride 132 = 66 dwords == 2 mod 32 -> fragment
// reads (addr = 66*l15 + 4*g4) hit all 32 banks at the 4-access minimum vs
// 136's 8-way pileup (R5 counter: 7.18M conflicts). Last-iteration
// redundant prefetch skipped (uniform branch).

typedef __attribute__((ext_vector_type(8))) short bf16x8;
typedef __attribute__((ext_vector_type(4))) float f32x4;

#define EPS_BN 1e-5f

__device__ __forceinline__ unsigned pk2(float a, float b){
  unsigned ua = __float_as_uint(a) + 0x8000u;
  unsigned ub = __float_as_uint(b) + 0x8000u;
  return __builtin_amdgcn_perm(ub, ua, 0x07060302);
}
__device__ __forceinline__ short f2bf(float a){
  unsigned u = __float_as_uint(a);
  u += 0x7FFFu + ((u >> 16) & 1u);
  return (short)(u >> 16);
}
__device__ __forceinline__ float lrelu(float v){ return fmaxf(v, 0.2f*v); }

// paired-uint2 LDS store/load (rows are 8B-aligned, not 16B)
__device__ __forceinline__ void st8(short* dst, float4 a, float4 b){
  *(uint2*)(dst)     = make_uint2(pk2(a.x,a.y), pk2(a.z,a.w));
  *(uint2*)(dst + 4) = make_uint2(pk2(b.x,b.y), pk2(b.z,b.w));
}
__device__ __forceinline__ bf16x8 ld8(const short* p){
  union { bf16x8 v; uint2 q[2]; } w;
  w.q[0] = *(const uint2*)(p);
  w.q[1] = *(const uint2*)(p + 4);
  return w.v;
}

// DPP row_ror reductions over the 16-lane row (l15 = k dimension)
template<int N>
__device__ __forceinline__ float ror16(float x){
  return __int_as_float(__builtin_amdgcn_mov_dpp(__float_as_int(x), 0x120+N, 0xF, 0xF, false));
}
__device__ __forceinline__ float rsum16(float v){
  v += ror16<1>(v); v += ror16<2>(v); v += ror16<4>(v); v += ror16<8>(v); return v;
}
__device__ __forceinline__ float rmax16(float v){
  v = fmaxf(v, ror16<1>(v)); v = fmaxf(v, ror16<2>(v));
  v = fmaxf(v, ror16<4>(v)); v = fmaxf(v, ror16<8>(v)); return v;
}

#define MFMA16(a,b,c) __builtin_amdgcn_mfma_f32_16x16x32_bf16((a),(b),(c),0,0,0)

__global__ __launch_bounds__(256, 2)
void gsl_fused(const float* __restrict__ x,       const float* __restrict__ rel_pos,
               const float* __restrict__ pos_w1,  const float* __restrict__ pos_g,
               const float* __restrict__ pos_bb,  const float* __restrict__ pos_m,
               const float* __restrict__ pos_v,   const float* __restrict__ pos_w2,
               const float* __restrict__ pos_b2,  const float* __restrict__ pe_w,
               const float* __restrict__ pe_b,    const float* __restrict__ trans_w,
               const float* __restrict__ tr_g,    const float* __restrict__ tr_bb,
               const float* __restrict__ tr_m,    const float* __restrict__ tr_v,
               const float* __restrict__ gate_w1, const float* __restrict__ ga_g,
               const float* __restrict__ ga_bb,   const float* __restrict__ ga_m,
               const float* __restrict__ ga_v,    const float* __restrict__ gate_w2,
               const float* __restrict__ gate_b2, const float* __restrict__ attn_w1,
               const float* __restrict__ at_g,    const float* __restrict__ at_bb,
               const float* __restrict__ at_m,    const float* __restrict__ at_v,
               const float* __restrict__ attn_w2, const float* __restrict__ attn_b2,
               float* __restrict__ out)
{
  // LDS map (70784 B, 2 blocks/CU):
  // [0,33792)      xbuf [128 cols][132] bf16; wave slice 8448B at wv*8448,
  //                aliased post-GEMM per wave: h1b [32][68] @0, gab [32][36] @4352
  // [33792,59136)  wmain [96][132] bf16 (trans 0..63, gate 64..79, attn 80..95)
  // [59136,68928)  wpos2 [72][68] bf16 (rows 0..63 pos_w2; 64..71 peW2 fold;
  //                A-frag junk reads rows 72..79 land in tabs -> harmless)
  // [68928,70784)  tabs f32: trQ[256] (s,b,pos_b2,0 quads) p1T[128] gaT[32]
  //                atT[32] peBt[16]
  __shared__ __align__(16) char smem[70784];
  short* xbuf  = (short*)smem;
  short* wmain = (short*)(smem + 33792);
  short* wpos2 = (short*)(smem + 59136);
  float* trQ  = (float*)(smem + 68928);
  float* p1T  = (float*)(smem + 69952);
  float* gaT  = (float*)(smem + 70464);
  float* atT  = (float*)(smem + 70592);
  float* peBt = (float*)(smem + 70720);

  const int tid = threadIdx.x;
  const int wv  = tid >> 6;
  const int l   = tid & 63;
  const int l15 = l & 15, g4 = l >> 4;
  const int bid = blockIdx.x;
  const int b    = bid >> 6;
  const int nblk = (bid & 63) << 5;

  // ---- stage weights -> LDS bf16 ----
  if (tid < 192){
    int r = tid >> 1, c0 = (tid & 1) * 64;
    const float* src = (r < 64) ? (trans_w + r*128)
                     : (r < 80) ? (gate_w1 + (r-64)*128)
                                : (attn_w1 + (r-80)*128);
    src += c0;
    short* dst = wmain + r*132 + c0;
    #pragma unroll
    for (int j = 0; j < 8; ++j)
      st8(dst + 8*j, *(const float4*)(src + 8*j), *(const float4*)(src + 8*j + 4));
  } else {
    int r = tid - 192;
    const float* src = pos_w2 + r*64;
    short* dst = wpos2 + r*68;
    #pragma unroll
    for (int j = 0; j < 8; ++j)
      st8(dst + 8*j, *(const float4*)(src + 8*j), *(const float4*)(src + 8*j + 4));
  }
  // ---- BN fold tables + peB const ----
  if (tid < 64){
    float s = tr_g[tid] * rsqrtf(tr_v[tid] + EPS_BN);
    *(float4*)(trQ + 4*tid) = make_float4(s, tr_bb[tid] - tr_m[tid]*s, pos_b2[tid], 0.f);
    float s2 = pos_g[tid] * rsqrtf(pos_v[tid] + EPS_BN);
    p1T[2*tid] = s2; p1T[2*tid+1] = pos_bb[tid] - pos_m[tid]*s2;
  } else if (tid < 80){
    int c = tid - 64;
    float s = ga_g[c] * rsqrtf(ga_v[c] + EPS_BN);
    gaT[2*c] = s; gaT[2*c+1] = ga_bb[c] - ga_m[c]*s;
  } else if (tid < 96){
    int c = tid - 80;
    float s = at_g[c] * rsqrtf(at_v[c] + EPS_BN);
    atT[2*c] = s; atT[2*c+1] = at_bb[c] - at_m[c]*s;
  } else if (tid < 112){
    int r2 = tid - 96;
    float v = 0.f;
    if (r2 < 8){
      v = pe_b[r2];
      for (int c = 0; c < 64; ++c) v += pe_w[r2*64 + c] * pos_b2[c];
    }
    peBt[r2] = v;
  }
  // ---- peW2 fold: rows 64..71 of wpos2 = pe_w @ pos_w2 ----
  {
    int o = 2*tid, r = o >> 6, j = o & 63;
    float c0 = 0.f, c1 = 0.f;
    for (int c = 0; c < 64; ++c){
      float a = pe_w[r*64 + c];
      c0 += a * pos_w2[c*64 + j];
      c1 += a * pos_w2[c*64 + j + 1];
    }
    *(unsigned*)(wpos2 + (64 + r)*68 + j) = pk2(c0, c1);
  }

  // ---- small weights / consts -> registers ----
  uint2 pw1p[4];
  #pragma unroll
  for (int m2 = 0; m2 < 4; ++m2){
    uint2 t = make_uint2(0u, 0u);
    if (g4 == 0){
      const float* rp = pos_w1 + (16*m2 + l15)*3;
      t.x = pk2(rp[0], rp[1]);
      t.y = pk2(rp[2], 0.f);
    }
    pw1p[m2] = t;
  }
  bf16x8 gaf;
  {
    bf16x8 t = {0,0,0,0,0,0,0,0};
    #pragma unroll
    for (int j = 0; j < 8; ++j){
      int k = 8*g4 + j;
      float v2 = 0.f;
      if (l15 < 8)       { if (k >= 16) v2 = attn_w2[l15*16 + (k-16)]; }
      else if (l15 == 8) { if (k < 16)  v2 = gate_w2[k]; }
      t[j] = f2bf(v2);
    }
    gaf = t;
  }
  const float gb2v = gate_b2[0];

  __syncthreads();   // LDS weights + tables visible

  float lcr[4];      // attn_b2 + peB combined logit const (needs peBt)
  #pragma unroll
  for (int r = 0; r < 4; ++r){
    int row = 4*g4 + r;
    lcr[r] = peBt[row] + ((row < 8) ? attn_b2[row] : 0.f);
  }

  // ---- per-wave constants ----
  const int col0 = 32*wv + l15, col1 = col0 + 16;
  const int lc0 = l15, lc1 = l15 + 16;
  const int lq = l & 7, ld = l >> 3;
  const int colb = 32*wv + 4*lq;
  char*  slice = smem + wv*8448;
  short* h1b   = (short*)slice;            // [32][68]
  short* gab   = (short*)(slice + 4352);   // [32][36]
  const float* xp0 = x + (((long)(b*128 + 8*ld)) << 16) + colb;
  const float* rpb = rel_pos + (((long)(3*b)) << 16);
  float* outb = out + (((long)(b*64)) << 11) + nblk + wv;

  // ---- prologue: prefetch iteration 0 ----
  f32x4 fa[8], fb[8];
  float rc[6] = {0.f,0.f,0.f,0.f,0.f,0.f};
  {
    const long sb0 = (long)nblk * 32;
    #pragma unroll
    for (int j = 0; j < 8; ++j) fa[j] = *(const f32x4*)(xp0 + sb0 + (((long)j) << 16));
    #pragma unroll
    for (int j = 0; j < 8; ++j) fb[j] = *(const f32x4*)(xp0 + sb0 + (((long)(64+j)) << 16));
    if (g4 == 0){
      long sg = sb0 + col0;
      rc[0] = rpb[sg];          rc[1] = rpb[sg + 65536];      rc[2] = rpb[sg + 131072];
      rc[3] = rpb[sg + 16];     rc[4] = rpb[sg + 65536 + 16]; rc[5] = rpb[sg + 131072 + 16];
    }
  }

  for (int it = 0; it < 8; ++it){
    const long sbase = (long)nblk*32 + 128*it;

    // (1) cvt + write staged tile -> own xbuf slice (consumes fa,fb)
    #pragma unroll
    for (int i2 = 0; i2 < 4; ++i2){
      short* dst = xbuf + (colb+i2)*132 + 8*ld;
      *(uint2*)(dst)      = make_uint2(pk2(fa[0][i2],fa[1][i2]), pk2(fa[2][i2],fa[3][i2]));
      *(uint2*)(dst + 4)  = make_uint2(pk2(fa[4][i2],fa[5][i2]), pk2(fa[6][i2],fa[7][i2]));
      *(uint2*)(dst + 64) = make_uint2(pk2(fb[0][i2],fb[1][i2]), pk2(fb[2][i2],fb[3][i2]));
      *(uint2*)(dst + 68) = make_uint2(pk2(fb[4][i2],fb[5][i2]), pk2(fb[6][i2],fb[7][i2]));
    }

    const long nsb = sbase + 128;
    // (2) prefetch fa half for next iter (in flight across GEMM)
    if (it < 7){
      #pragma unroll
      for (int j = 0; j < 8; ++j) fa[j] = *(const f32x4*)(xp0 + nsb + (((long)j) << 16));
    }

    // (3) main GEMM: [96x128] @ xtile
    f32x4 acc[6][2];
    #pragma unroll
    for (int m = 0; m < 6; ++m){
      f32x4 z = {0.f,0.f,0.f,0.f};
      acc[m][0] = z; acc[m][1] = z;
    }
    #pragma unroll
    for (int ks = 0; ks < 4; ++ks){
      bf16x8 b0 = ld8(xbuf + col0*132 + 32*ks + 8*g4);
      bf16x8 b1 = ld8(xbuf + col1*132 + 32*ks + 8*g4);
      #pragma unroll
      for (int m = 0; m < 6; ++m){
        bf16x8 af = ld8(wmain + (16*m + l15)*132 + 32*ks + 8*g4);
        acc[m][0] = MFMA16(af, b0, acc[m][0]);
        acc[m][1] = MFMA16(af, b1, acc[m][1]);
      }
    }

    // (4) prefetch fb half for next iter (in flight across epilogue)
    if (it < 7){
      #pragma unroll
      for (int j = 0; j < 8; ++j) fb[j] = *(const f32x4*)(xp0 + nsb + (((long)(64+j)) << 16));
    }

    // (5) pos layer 1 (K padded 3->32) -> h1b ; uses rc of CURRENT iter
    {
      bf16x8 rf0 = {0,0,0,0,0,0,0,0}, rf1 = {0,0,0,0,0,0,0,0};
      if (g4 == 0){
        union { bf16x8 v; unsigned u[4]; } t0, t1;
        t0.u[0] = pk2(rc[0], rc[1]); t0.u[1] = pk2(rc[2], 0.f); t0.u[2] = 0u; t0.u[3] = 0u;
        t1.u[0] = pk2(rc[3], rc[4]); t1.u[1] = pk2(rc[5], 0.f); t1.u[2] = 0u; t1.u[3] = 0u;
        rf0 = t0.v; rf1 = t1.v;
      }
      #pragma unroll
      for (int m2 = 0; m2 < 4; ++m2){
        union { bf16x8 v; unsigned u[4]; } aw;
        aw.u[0] = pw1p[m2].x; aw.u[1] = pw1p[m2].y; aw.u[2] = 0u; aw.u[3] = 0u;
        f32x4 z = {0.f,0.f,0.f,0.f};
        f32x4 d0 = MFMA16(aw.v, rf0, z);
        f32x4 d1 = MFMA16(aw.v, rf1, z);
        int cb2 = 16*m2 + 4*g4;
        float2 t0 = *(const float2*)(p1T + 2*(cb2+0));
        float2 t1 = *(const float2*)(p1T + 2*(cb2+1));
        float2 t2 = *(const float2*)(p1T + 2*(cb2+2));
        float2 t3 = *(const float2*)(p1T + 2*(cb2+3));
        float h0 = lrelu(t0.x*d0[0]+t0.y), h1v = lrelu(t1.x*d0[1]+t1.y);
        float h2 = lrelu(t2.x*d0[2]+t2.y), h3 = lrelu(t3.x*d0[3]+t3.y);
        *(uint2*)(h1b + lc0*68 + cb2) = make_uint2(pk2(h0,h1v), pk2(h2,h3));
        h0 = lrelu(t0.x*d1[0]+t0.y); h1v = lrelu(t1.x*d1[1]+t1.y);
        h2 = lrelu(t2.x*d1[2]+t2.y); h3 = lrelu(t3.x*d1[3]+t3.y);
        *(uint2*)(h1b + lc1*68 + cb2) = make_uint2(pk2(h0,h1v), pk2(h2,h3));
      }
    }
    // (5b) prefetch rel_pos for NEXT iter (after use)
    if (g4 == 0 && it < 7){
      long sg = nsb + col0;
      rc[0] = rpb[sg];          rc[1] = rpb[sg + 65536];      rc[2] = rpb[sg + 131072];
      rc[3] = rpb[sg + 16];     rc[4] = rpb[sg + 65536 + 16]; rc[5] = rpb[sg + 131072 + 16];
    }

    // (6) trans epilogue FIRST: acc[0..3] = lrelu(BN(conv)) + pos_b2
    #pragma unroll
    for (int m = 0; m < 4; ++m)
      #pragma unroll
      for (int r = 0; r < 4; ++r){
        float4 tq = *(const float4*)(trQ + 4*(16*m + 4*g4 + r));
        acc[m][0][r] = lrelu(tq.x*acc[m][0][r] + tq.y) + tq.z;
        acc[m][1][r] = lrelu(tq.x*acc[m][1][r] + tq.y) + tq.z;
      }

    // (7) pos2 MFMAs accumulate INTO acc[0..3]; pe-fold rows -> pac4
    f32x4 pac4[2];
    {
      f32x4 z = {0.f,0.f,0.f,0.f};
      pac4[0] = z; pac4[1] = z;
    }
    #pragma unroll
    for (int ks = 0; ks < 2; ++ks){
      bf16x8 h0 = ld8(h1b + lc0*68 + 32*ks + 8*g4);
      bf16x8 h1v = ld8(h1b + lc1*68 + 32*ks + 8*g4);
      #pragma unroll
      for (int m2 = 0; m2 < 4; ++m2){
        bf16x8 af = ld8(wpos2 + (16*m2 + l15)*68 + 32*ks + 8*g4);
        acc[m2][0] = MFMA16(af, h0, acc[m2][0]);
        acc[m2][1] = MFMA16(af, h1v, acc[m2][1]);
      }
      bf16x8 af4 = ld8(wpos2 + (64 + l15)*68 + 32*ks + 8*g4);
      pac4[0] = MFMA16(af4, h0, pac4[0]);
      pac4[1] = MFMA16(af4, h1v, pac4[1]);
    }

    // (8) hidden epilogues -> gab (gate_h ch 0..15, attn_h ch 16..31)
    {
      int hc = 4*g4;
      float2 g0p = *(const float2*)(gaT + 2*(hc+0));
      float2 g1p = *(const float2*)(gaT + 2*(hc+1));
      float2 g2p = *(const float2*)(gaT + 2*(hc+2));
      float2 g3p = *(const float2*)(gaT + 2*(hc+3));
      float2 a0p = *(const float2*)(atT + 2*(hc+0));
      float2 a1p = *(const float2*)(atT + 2*(hc+1));
      float2 a2p = *(const float2*)(atT + 2*(hc+2));
      float2 a3p = *(const float2*)(atT + 2*(hc+3));
      #pragma unroll
      for (int ct = 0; ct < 2; ++ct){
        int lc = (ct == 0) ? lc0 : lc1;
        float q0 = lrelu(g0p.x*acc[4][ct][0] + g0p.y), q1 = lrelu(g1p.x*acc[4][ct][1] + g1p.y);
        float q2 = lrelu(g2p.x*acc[4][ct][2] + g2p.y), q3 = lrelu(g3p.x*acc[4][ct][3] + g3p.y);
        *(uint2*)(gab + lc*36 + hc) = make_uint2(pk2(q0,q1), pk2(q2,q3));
        float a0 = lrelu(a0p.x*acc[5][ct][0] + a0p.y), a1 = lrelu(a1p.x*acc[5][ct][1] + a1p.y);
        float a2 = lrelu(a2p.x*acc[5][ct][2] + a2p.y), a3 = lrelu(a3p.x*acc[5][ct][3] + a3p.y);
        *(uint2*)(gab + lc*36 + 16 + hc) = make_uint2(pk2(a0,a1), pk2(a2,a3));
      }
    }

    // (9) gate/attn layer-2 MFMA (rows 0..7 attn, row 8 gate)
    f32x4 gac0 = {0.f,0.f,0.f,0.f}, gac1 = gac0;
    {
      bf16x8 g0 = ld8(gab + lc0*36 + 8*g4);
      bf16x8 g1 = ld8(gab + lc1*36 + 8*g4);
      gac0 = MFMA16(gaf, g0, gac0);
      gac1 = MFMA16(gaf, g1, gac1);
    }

    // (10) gate, logits, softmax over k (DPP reduce), direct stores
    float gv0 = __shfl(gac0[0], 32 + l15, 64);
    float gv1 = __shfl(gac1[0], 32 + l15, 64);
    float gm0 = 1.f/(1.f + __expf(-(gv0 + gb2v)));
    float gm1 = 1.f/(1.f + __expf(-(gv1 + gb2v)));
    float lg0 = __logf(gm0 + 1e-6f), lg1 = __logf(gm1 + 1e-6f);

    float wg0[4], wg1[4];
    #pragma unroll
    for (int r = 0; r < 4; ++r){
      float t0 = gac0[r] + pac4[0][r] + lcr[r] + lg0;
      float t1 = gac1[r] + pac4[1][r] + lcr[r] + lg1;
      float mx = rmax16(fmaxf(t0, t1));
      float e0 = __expf(t0 - mx), e1 = __expf(t1 - mx);
      float inv = 1.f / rsum16(e0 + e1);
      wg0[r] = e0 * inv; wg1[r] = e1 * inv;
    }
    float wf0[8], wf1[8];
    #pragma unroll
    for (int gg = 0; gg < 8; ++gg){
      int src = 16*(gg >> 2) + l15;
      wf0[gg] = __shfl(wg0[gg & 3], src, 64);
      wf1[gg] = __shfl(wg1[gg & 3], src, 64);
    }
    const bool hi = (g4 >= 2);
    #pragma unroll
    for (int m = 0; m < 4; ++m){
      float w0 = hi ? wf0[2*m+1] : wf0[2*m];
      float w1 = hi ? wf1[2*m+1] : wf1[2*m];
      #pragma unroll
      for (int r = 0; r < 4; ++r){
        float sA = rsum16(acc[m][0][r]*w0 + acc[m][1][r]*w1);
        float sM = rmax16(fmaxf(acc[m][0][r]*gm0, acc[m][1][r]*gm1));
        if (l15 == 0)
          outb[(((long)(16*m + 4*g4 + r)) << 11) + 4*it] = sA + sM;
      }
    }
  }
}

extern "C" void kernel_launch(void* const* d_in, const int* in_sizes, int n_in,
                              void* d_out, int out_size, void* d_ws, size_t ws_size,
                              hipStream_t stream){
  (void)in_sizes; (void)n_in; (void)out_size; (void)d_ws; (void)ws_size;
  gsl_fused<<<dim3(512), dim3(256), 0, stream>>>(
    (const float*)d_in[0],  (const float*)d_in[1],  (const float*)d_in[2],
    (const float*)d_in[3],  (const float*)d_in[4],  (const float*)d_in[5],
    (const float*)d_in[6],  (const float*)d_in[7],  (const float*)d_in[8],
    (const float*)d_in[9],  (const float*)d_in[10], (const float*)d_in[11],
    (const float*)d_in[12], (const float*)d_in[13], (const float*)d_in[14],
    (const float*)d_in[15], (const float*)d_in[16], (const float*)d_in[17],
    (const float*)d_in[18], (const float*)d_in[19], (const float*)d_in[20],
    (const float*)d_in[21], (const float*)d_in[22], (const float*)d_in[23],
    (const float*)d_in[24], (const float*)d_in[25], (const float*)d_in[26],
    (const float*)d_in[27], (const float*)d_in[28], (const float*)d_in[29],
    (float*)d_out);
}

// Round 11
// 70.029 us; speedup vs baseline: 3.1216x; 1.0773x over previous
//
#include <hip/hip_runtime.h>

// Grouped_Soft_GSL_Block_PE fused kernel for MI355X (gfx950).
// B=8, IC2=128, N=2048, K=32, C=64, G=8, CPG=8, hidden=16.
// R11: R10 structure (512 blocks, 256 thr / 4 waves, block owns 32 n,
// 8 iterations of 4 n, zero barriers in loop, bank-optimal strides 132/68/36)
// with: (a) epilogue reduce-scatter butterfly (15+15 shfl/op for all 16
// sums+maxes, distributed result -> one 64-lane store covering all 64
// channels) replacing 32 full 16-lane reductions + masked stores;
// (b) peW2/peBt fold moved to prep kernel (d_ws).

typedef __attribute__((ext_vector_type(8))) short bf16x8;
typedef __attribute__((ext_vector_type(4))) float f32x4;

#define EPS_BN 1e-5f

__device__ __forceinline__ unsigned pk2(float a, float b){
  unsigned ua = __float_as_uint(a) + 0x8000u;
  unsigned ub = __float_as_uint(b) + 0x8000u;
  return __builtin_amdgcn_perm(ub, ua, 0x07060302);
}
__device__ __forceinline__ short f2bf(float a){
  unsigned u = __float_as_uint(a);
  u += 0x7FFFu + ((u >> 16) & 1u);
  return (short)(u >> 16);
}
__device__ __forceinline__ float lrelu(float v){ return fmaxf(v, 0.2f*v); }

__device__ __forceinline__ void st8(short* dst, float4 a, float4 b){
  *(uint2*)(dst)     = make_uint2(pk2(a.x,a.y), pk2(a.z,a.w));
  *(uint2*)(dst + 4) = make_uint2(pk2(b.x,b.y), pk2(b.z,b.w));
}
__device__ __forceinline__ bf16x8 ld8(const short* p){
  union { bf16x8 v; uint2 q[2]; } w;
  w.q[0] = *(const uint2*)(p);
  w.q[1] = *(const uint2*)(p + 4);
  return w.v;
}

// DPP row_ror reductions over the 16-lane row (l15 = k dimension)
template<int N>
__device__ __forceinline__ float ror16(float x){
  return __int_as_float(__builtin_amdgcn_mov_dpp(__float_as_int(x), 0x120+N, 0xF, 0xF, false));
}
__device__ __forceinline__ float rsum16(float v){
  v += ror16<1>(v); v += ror16<2>(v); v += ror16<4>(v); v += ror16<8>(v); return v;
}
__device__ __forceinline__ float rmax16(float v){
  v = fmaxf(v, ror16<1>(v)); v = fmaxf(v, ror16<2>(v));
  v = fmaxf(v, ror16<4>(v)); v = fmaxf(v, ror16<8>(v)); return v;
}

#define MFMA16(a,b,c) __builtin_amdgcn_mfma_f32_16x16x32_bf16((a),(b),(c),0,0,0)

// prep: peW2 = pe_w @ pos_w2 (8x64, row-major) -> ws[0..511]; peBt -> ws[512..527]
__global__ void gsl_prep(const float* __restrict__ pos_w2, const float* __restrict__ pe_w,
                         const float* __restrict__ pe_b,   const float* __restrict__ pos_b2,
                         float* __restrict__ ws){
  int t = threadIdx.x;            // 0..511
  int r = t >> 6, j = t & 63;
  float s = 0.f;
  for (int c = 0; c < 64; ++c) s += pe_w[r*64 + c] * pos_w2[c*64 + j];
  ws[t] = s;
  if (t < 16){
    float v = 0.f;
    if (t < 8){
      v = pe_b[t];
      for (int c = 0; c < 64; ++c) v += pe_w[t*64 + c] * pos_b2[c];
    }
    ws[512 + t] = v;
  }
}

__global__ __launch_bounds__(256, 2)
void gsl_fused(const float* __restrict__ x,       const float* __restrict__ rel_pos,
               const float* __restrict__ pos_w1,  const float* __restrict__ pos_g,
               const float* __restrict__ pos_bb,  const float* __restrict__ pos_m,
               const float* __restrict__ pos_v,   const float* __restrict__ pos_w2,
               const float* __restrict__ pos_b2,  const float* __restrict__ trans_w,
               const float* __restrict__ tr_g,    const float* __restrict__ tr_bb,
               const float* __restrict__ tr_m,    const float* __restrict__ tr_v,
               const float* __restrict__ gate_w1, const float* __restrict__ ga_g,
               const float* __restrict__ ga_bb,   const float* __restrict__ ga_m,
               const float* __restrict__ ga_v,    const float* __restrict__ gate_w2,
               const float* __restrict__ gate_b2, const float* __restrict__ attn_w1,
               const float* __restrict__ at_g,    const float* __restrict__ at_bb,
               const float* __restrict__ at_m,    const float* __restrict__ at_v,
               const float* __restrict__ attn_w2, const float* __restrict__ attn_b2,
               const float* __restrict__ ws,      float* __restrict__ out)
{
  // LDS map (70784 B, 2 blocks/CU):
  // [0,33792)      xbuf [128 cols][132] bf16; wave slice 8448B at wv*8448,
  //                aliased post-GEMM per wave: h1b [32][68] @0, gab [32][36] @4352
  // [33792,59136)  wmain [96][132] bf16 (trans 0..63, gate 64..79, attn 80..95)
  // [59136,68928)  wpos2 [72][68] bf16 (rows 0..63 pos_w2; 64..71 peW2 from ws;
  //                A-frag junk reads rows 72..79 land in tabs -> harmless)
  // [68928,70784)  tabs f32: trQ[256] (s,b,pos_b2,0 quads) p1T[128] gaT[32] atT[32]
  __shared__ __align__(16) char smem[70784];
  short* xbuf  = (short*)smem;
  short* wmain = (short*)(smem + 33792);
  short* wpos2 = (short*)(smem + 59136);
  float* trQ  = (float*)(smem + 68928);
  float* p1T  = (float*)(smem + 69952);
  float* gaT  = (float*)(smem + 70464);
  float* atT  = (float*)(smem + 70592);

  const int tid = threadIdx.x;
  const int wv  = tid >> 6;
  const int l   = tid & 63;
  const int l15 = l & 15, g4 = l >> 4;
  const int bid = blockIdx.x;
  const int b    = bid >> 6;
  const int nblk = (bid & 63) << 5;

  // ---- stage weights -> LDS bf16 ----
  if (tid < 192){
    int r = tid >> 1, c0 = (tid & 1) * 64;
    const float* src = (r < 64) ? (trans_w + r*128)
                     : (r < 80) ? (gate_w1 + (r-64)*128)
                                : (attn_w1 + (r-80)*128);
    src += c0;
    short* dst = wmain + r*132 + c0;
    #pragma unroll
    for (int j = 0; j < 8; ++j)
      st8(dst + 8*j, *(const float4*)(src + 8*j), *(const float4*)(src + 8*j + 4));
  } else {
    int r = tid - 192;
    const float* src = pos_w2 + r*64;
    short* dst = wpos2 + r*68;
    #pragma unroll
    for (int j = 0; j < 8; ++j)
      st8(dst + 8*j, *(const float4*)(src + 8*j), *(const float4*)(src + 8*j + 4));
  }
  // peW2 rows 64..71 of wpos2 from ws
  if (tid < 16){
    int r = tid >> 1, c0 = (tid & 1) * 32;
    const float* src = ws + r*64 + c0;
    short* dst = wpos2 + (64 + r)*68 + c0;
    #pragma unroll
    for (int j = 0; j < 4; ++j)
      st8(dst + 8*j, *(const float4*)(src + 8*j), *(const float4*)(src + 8*j + 4));
  }
  // ---- BN fold tables ----
  if (tid < 64){
    float s = tr_g[tid] * rsqrtf(tr_v[tid] + EPS_BN);
    *(float4*)(trQ + 4*tid) = make_float4(s, tr_bb[tid] - tr_m[tid]*s, pos_b2[tid], 0.f);
    float s2 = pos_g[tid] * rsqrtf(pos_v[tid] + EPS_BN);
    p1T[2*tid] = s2; p1T[2*tid+1] = pos_bb[tid] - pos_m[tid]*s2;
  } else if (tid < 80){
    int c = tid - 64;
    float s = ga_g[c] * rsqrtf(ga_v[c] + EPS_BN);
    gaT[2*c] = s; gaT[2*c+1] = ga_bb[c] - ga_m[c]*s;
  } else if (tid < 96){
    int c = tid - 80;
    float s = at_g[c] * rsqrtf(at_v[c] + EPS_BN);
    atT[2*c] = s; atT[2*c+1] = at_bb[c] - at_m[c]*s;
  }

  // ---- small weights / consts -> registers ----
  uint2 pw1p[4];
  #pragma unroll
  for (int m2 = 0; m2 < 4; ++m2){
    uint2 t = make_uint2(0u, 0u);
    if (g4 == 0){
      const float* rp = pos_w1 + (16*m2 + l15)*3;
      t.x = pk2(rp[0], rp[1]);
      t.y = pk2(rp[2], 0.f);
    }
    pw1p[m2] = t;
  }
  bf16x8 gaf;
  {
    bf16x8 t = {0,0,0,0,0,0,0,0};
    #pragma unroll
    for (int j = 0; j < 8; ++j){
      int k = 8*g4 + j;
      float v2 = 0.f;
      if (l15 < 8)       { if (k >= 16) v2 = attn_w2[l15*16 + (k-16)]; }
      else if (l15 == 8) { if (k < 16)  v2 = gate_w2[k]; }
      t[j] = f2bf(v2);
    }
    gaf = t;
  }
  const float gb2v = gate_b2[0];
  float lcr[4];      // attn_b2 + peBt combined logit const
  #pragma unroll
  for (int r = 0; r < 4; ++r){
    int row = 4*g4 + r;
    lcr[r] = ws[512 + row] + ((row < 8) ? attn_b2[row] : 0.f);
  }

  // ---- per-wave constants ----
  const int col0 = 32*wv + l15, col1 = col0 + 16;
  const int lc0 = l15, lc1 = l15 + 16;
  const int lq = l & 7, ld = l >> 3;
  const int colb = 32*wv + 4*lq;
  char*  slice = smem + wv*8448;
  short* h1b   = (short*)slice;            // [32][68]
  short* gab   = (short*)(slice + 4352);   // [32][36]
  const float* xp0 = x + (((long)(b*128 + 8*ld)) << 16) + colb;
  const float* rpb = rel_pos + (((long)(3*b)) << 16);
  const int och = 16*(l15 >> 2) + 4*g4 + (l15 & 3);   // butterfly output channel
  float* outb = out + (((long)(b*64 + och)) << 11) + nblk + wv;

  // ---- prologue: prefetch iteration 0 ----
  f32x4 fa[8], fb[8];
  float rc[6] = {0.f,0.f,0.f,0.f,0.f,0.f};
  {
    const long sb0 = (long)nblk * 32;
    #pragma unroll
    for (int j = 0; j < 8; ++j) fa[j] = *(const f32x4*)(xp0 + sb0 + (((long)j) << 16));
    #pragma unroll
    for (int j = 0; j < 8; ++j) fb[j] = *(const f32x4*)(xp0 + sb0 + (((long)(64+j)) << 16));
    if (g4 == 0){
      long sg = sb0 + col0;
      rc[0] = rpb[sg];          rc[1] = rpb[sg + 65536];      rc[2] = rpb[sg + 131072];
      rc[3] = rpb[sg + 16];     rc[4] = rpb[sg + 65536 + 16]; rc[5] = rpb[sg + 131072 + 16];
    }
  }

  __syncthreads();   // LDS weights + tables visible

  for (int it = 0; it < 8; ++it){
    const long sbase = (long)nblk*32 + 128*it;

    // (1) cvt + write staged tile -> own xbuf slice (consumes fa,fb)
    #pragma unroll
    for (int i2 = 0; i2 < 4; ++i2){
      short* dst = xbuf + (colb+i2)*132 + 8*ld;
      *(uint2*)(dst)      = make_uint2(pk2(fa[0][i2],fa[1][i2]), pk2(fa[2][i2],fa[3][i2]));
      *(uint2*)(dst + 4)  = make_uint2(pk2(fa[4][i2],fa[5][i2]), pk2(fa[6][i2],fa[7][i2]));
      *(uint2*)(dst + 64) = make_uint2(pk2(fb[0][i2],fb[1][i2]), pk2(fb[2][i2],fb[3][i2]));
      *(uint2*)(dst + 68) = make_uint2(pk2(fb[4][i2],fb[5][i2]), pk2(fb[6][i2],fb[7][i2]));
    }

    const long nsb = sbase + 128;
    // (2) prefetch fa half for next iter (in flight across GEMM)
    if (it < 7){
      #pragma unroll
      for (int j = 0; j < 8; ++j) fa[j] = *(const f32x4*)(xp0 + nsb + (((long)j) << 16));
    }

    // (3) main GEMM: [96x128] @ xtile
    f32x4 acc[6][2];
    #pragma unroll
    for (int m = 0; m < 6; ++m){
      f32x4 z = {0.f,0.f,0.f,0.f};
      acc[m][0] = z; acc[m][1] = z;
    }
    #pragma unroll
    for (int ks = 0; ks < 4; ++ks){
      bf16x8 b0 = ld8(xbuf + col0*132 + 32*ks + 8*g4);
      bf16x8 b1 = ld8(xbuf + col1*132 + 32*ks + 8*g4);
      #pragma unroll
      for (int m = 0; m < 6; ++m){
        bf16x8 af = ld8(wmain + (16*m + l15)*132 + 32*ks + 8*g4);
        acc[m][0] = MFMA16(af, b0, acc[m][0]);
        acc[m][1] = MFMA16(af, b1, acc[m][1]);
      }
    }

    // (4) prefetch fb half for next iter (in flight across epilogue)
    if (it < 7){
      #pragma unroll
      for (int j = 0; j < 8; ++j) fb[j] = *(const f32x4*)(xp0 + nsb + (((long)(64+j)) << 16));
    }

    // (5) pos layer 1 (K padded 3->32) -> h1b ; uses rc of CURRENT iter
    {
      bf16x8 rf0 = {0,0,0,0,0,0,0,0}, rf1 = {0,0,0,0,0,0,0,0};
      if (g4 == 0){
        union { bf16x8 v; unsigned u[4]; } t0, t1;
        t0.u[0] = pk2(rc[0], rc[1]); t0.u[1] = pk2(rc[2], 0.f); t0.u[2] = 0u; t0.u[3] = 0u;
        t1.u[0] = pk2(rc[3], rc[4]); t1.u[1] = pk2(rc[5], 0.f); t1.u[2] = 0u; t1.u[3] = 0u;
        rf0 = t0.v; rf1 = t1.v;
      }
      #pragma unroll
      for (int m2 = 0; m2 < 4; ++m2){
        union { bf16x8 v; unsigned u[4]; } aw;
        aw.u[0] = pw1p[m2].x; aw.u[1] = pw1p[m2].y; aw.u[2] = 0u; aw.u[3] = 0u;
        f32x4 z = {0.f,0.f,0.f,0.f};
        f32x4 d0 = MFMA16(aw.v, rf0, z);
        f32x4 d1 = MFMA16(aw.v, rf1, z);
        int cb2 = 16*m2 + 4*g4;
        float2 t0 = *(const float2*)(p1T + 2*(cb2+0));
        float2 t1 = *(const float2*)(p1T + 2*(cb2+1));
        float2 t2 = *(const float2*)(p1T + 2*(cb2+2));
        float2 t3 = *(const float2*)(p1T + 2*(cb2+3));
        float h0 = lrelu(t0.x*d0[0]+t0.y), h1v = lrelu(t1.x*d0[1]+t1.y);
        float h2 = lrelu(t2.x*d0[2]+t2.y), h3 = lrelu(t3.x*d0[3]+t3.y);
        *(uint2*)(h1b + lc0*68 + cb2) = make_uint2(pk2(h0,h1v), pk2(h2,h3));
        h0 = lrelu(t0.x*d1[0]+t0.y); h1v = lrelu(t1.x*d1[1]+t1.y);
        h2 = lrelu(t2.x*d1[2]+t2.y); h3 = lrelu(t3.x*d1[3]+t3.y);
        *(uint2*)(h1b + lc1*68 + cb2) = make_uint2(pk2(h0,h1v), pk2(h2,h3));
      }
    }
    // (5b) prefetch rel_pos for NEXT iter (after use)
    if (g4 == 0 && it < 7){
      long sg = nsb + col0;
      rc[0] = rpb[sg];          rc[1] = rpb[sg + 65536];      rc[2] = rpb[sg + 131072];
      rc[3] = rpb[sg + 16];     rc[4] = rpb[sg + 65536 + 16]; rc[5] = rpb[sg + 131072 + 16];
    }

    // (6) trans epilogue FIRST: acc[0..3] = lrelu(BN(conv)) + pos_b2
    #pragma unroll
    for (int m = 0; m < 4; ++m)
      #pragma unroll
      for (int r = 0; r < 4; ++r){
        float4 tq = *(const float4*)(trQ + 4*(16*m + 4*g4 + r));
        acc[m][0][r] = lrelu(tq.x*acc[m][0][r] + tq.y) + tq.z;
        acc[m][1][r] = lrelu(tq.x*acc[m][1][r] + tq.y) + tq.z;
      }

    // (7) pos2 MFMAs accumulate INTO acc[0..3]; pe-fold rows -> pac4
    f32x4 pac4[2];
    {
      f32x4 z = {0.f,0.f,0.f,0.f};
      pac4[0] = z; pac4[1] = z;
    }
    #pragma unroll
    for (int ks = 0; ks < 2; ++ks){
      bf16x8 h0 = ld8(h1b + lc0*68 + 32*ks + 8*g4);
      bf16x8 h1v = ld8(h1b + lc1*68 + 32*ks + 8*g4);
      #pragma unroll
      for (int m2 = 0; m2 < 4; ++m2){
        bf16x8 af = ld8(wpos2 + (16*m2 + l15)*68 + 32*ks + 8*g4);
        acc[m2][0] = MFMA16(af, h0, acc[m2][0]);
        acc[m2][1] = MFMA16(af, h1v, acc[m2][1]);
      }
      bf16x8 af4 = ld8(wpos2 + (64 + l15)*68 + 32*ks + 8*g4);
      pac4[0] = MFMA16(af4, h0, pac4[0]);
      pac4[1] = MFMA16(af4, h1v, pac4[1]);
    }

    // (8) hidden epilogues -> gab (gate_h ch 0..15, attn_h ch 16..31)
    {
      int hc = 4*g4;
      float2 g0p = *(const float2*)(gaT + 2*(hc+0));
      float2 g1p = *(const float2*)(gaT + 2*(hc+1));
      float2 g2p = *(const float2*)(gaT + 2*(hc+2));
      float2 g3p = *(const float2*)(gaT + 2*(hc+3));
      float2 a0p = *(const float2*)(atT + 2*(hc+0));
      float2 a1p = *(const float2*)(atT + 2*(hc+1));
      float2 a2p = *(const float2*)(atT + 2*(hc+2));
      float2 a3p = *(const float2*)(atT + 2*(hc+3));
      #pragma unroll
      for (int ct = 0; ct < 2; ++ct){
        int lc = (ct == 0) ? lc0 : lc1;
        float q0 = lrelu(g0p.x*acc[4][ct][0] + g0p.y), q1 = lrelu(g1p.x*acc[4][ct][1] + g1p.y);
        float q2 = lrelu(g2p.x*acc[4][ct][2] + g2p.y), q3 = lrelu(g3p.x*acc[4][ct][3] + g3p.y);
        *(uint2*)(gab + lc*36 + hc) = make_uint2(pk2(q0,q1), pk2(q2,q3));
        float a0 = lrelu(a0p.x*acc[5][ct][0] + a0p.y), a1 = lrelu(a1p.x*acc[5][ct][1] + a1p.y);
        float a2 = lrelu(a2p.x*acc[5][ct][2] + a2p.y), a3 = lrelu(a3p.x*acc[5][ct][3] + a3p.y);
        *(uint2*)(gab + lc*36 + 16 + hc) = make_uint2(pk2(a0,a1), pk2(a2,a3));
      }
    }

    // (9) gate/attn layer-2 MFMA (rows 0..7 attn, row 8 gate)
    f32x4 gac0 = {0.f,0.f,0.f,0.f}, gac1 = gac0;
    {
      bf16x8 g0 = ld8(gab + lc0*36 + 8*g4);
      bf16x8 g1 = ld8(gab + lc1*36 + 8*g4);
      gac0 = MFMA16(gaf, g0, gac0);
      gac1 = MFMA16(gaf, g1, gac1);
    }

    // (10) gate + logits + softmax over k (DPP reduce)
    float gv0 = __shfl(gac0[0], 32 + l15, 64);
    float gv1 = __shfl(gac1[0], 32 + l15, 64);
    float gm0 = 1.f/(1.f + __expf(-(gv0 + gb2v)));
    float gm1 = 1.f/(1.f + __expf(-(gv1 + gb2v)));
    float lg0 = __logf(gm0 + 1e-6f), lg1 = __logf(gm1 + 1e-6f);

    float wg0[4], wg1[4];
    #pragma unroll
    for (int r = 0; r < 4; ++r){
      float t0 = gac0[r] + pac4[0][r] + lcr[r] + lg0;
      float t1 = gac1[r] + pac4[1][r] + lcr[r] + lg1;
      float mx = rmax16(fmaxf(t0, t1));
      float e0 = __expf(t0 - mx), e1 = __expf(t1 - mx);
      float inv = 1.f / rsum16(e0 + e1);
      wg0[r] = e0 * inv; wg1[r] = e1 * inv;
    }

    // (11) fill vA/vM (weighted / gated values) then reduce-scatter butterfly
    float vA[16], vM[16];
    const bool hi = (g4 >= 2);
    #pragma unroll
    for (int m = 0; m < 4; ++m){
      int src = 16*(m >> 1) + l15;
      float a0 = __shfl(wg0[(2*m) & 3],   src, 64);
      float b0 = __shfl(wg0[(2*m+1) & 3], src, 64);
      float a1 = __shfl(wg1[(2*m) & 3],   src, 64);
      float b1 = __shfl(wg1[(2*m+1) & 3], src, 64);
      float w0 = hi ? b0 : a0;
      float w1 = hi ? b1 : a1;
      #pragma unroll
      for (int r = 0; r < 4; ++r){
        vA[4*m+r] = acc[m][0][r]*w0 + acc[m][1][r]*w1;
        vM[4*m+r] = fmaxf(acc[m][0][r]*gm0, acc[m][1][r]*gm1);
      }
    }
    // recursive-halving over l15: after 4 stages lane l15 holds index l15
    #pragma unroll
    for (int s = 0; s < 4; ++s){
      const int mm = 8 >> s;
      const bool up = (l15 & mm) != 0;
      #pragma unroll
      for (int k2 = 0; k2 < mm; ++k2){
        float sendA = up ? vA[k2] : vA[k2 + mm];
        float keepA = up ? vA[k2 + mm] : vA[k2];
        vA[k2] = keepA + __shfl_xor(sendA, mm, 64);
        float sendM = up ? vM[k2] : vM[k2 + mm];
        float keepM = up ? vM[k2 + mm] : vM[k2];
        vM[k2] = fmaxf(keepM, __shfl_xor(sendM, mm, 64));
      }
    }
    // lane (g4,l15) holds channel och = 16*(l15>>2)+4*g4+(l15&3); n = nblk+4it+wv
    outb[4*it] = vA[0] + vM[0];
  }
}

extern "C" void kernel_launch(void* const* d_in, const int* in_sizes, int n_in,
                              void* d_out, int out_size, void* d_ws, size_t ws_size,
                              hipStream_t stream){
  (void)in_sizes; (void)n_in; (void)out_size; (void)ws_size;
  gsl_prep<<<dim3(1), dim3(512), 0, stream>>>(
    (const float*)d_in[7], (const float*)d_in[9], (const float*)d_in[10],
    (const float*)d_in[8], (float*)d_ws);
  gsl_fused<<<dim3(512), dim3(256), 0, stream>>>(
    (const float*)d_in[0],  (const float*)d_in[1],  (const float*)d_in[2],
    (const float*)d_in[3],  (const float*)d_in[4],  (const float*)d_in[5],
    (const float*)d_in[6],  (const float*)d_in[7],  (const float*)d_in[8],
    (const float*)d_in[11], (const float*)d_in[12], (const float*)d_in[13],
    (const float*)d_in[14], (const float*)d_in[15], (const float*)d_in[16],
    (const float*)d_in[17], (const float*)d_in[18], (const float*)d_in[19],
    (const float*)d_in[20], (const float*)d_in[21], (const float*)d_in[22],
    (const float*)d_in[23], (const float*)d_in[24], (const float*)d_in[25],
    (const float*)d_in[26], (const float*)d_in[27], (const float*)d_in[28],
    (const float*)d_in[29], (const float*)d_ws, (float*)d_out);
}